// Round 1
// 560.111 us; speedup vs baseline: 1.0849x; 1.0849x over previous
//
#include <hip/hip_runtime.h>
#include <math.h>

#define NUM_USERS 100000
#define NUM_ITEMS 50000
#define NN 150000
#define DD 64
#define EE 1250000
#define SS 400000
#define TAU 0.2f
#define EDGE_BIAS 0.5f
#define NB_SCAN 586  // ceil(NN/256)

typedef __attribute__((ext_vector_type(8))) _Float16 f16x8;
typedef __attribute__((ext_vector_type(2))) _Float16 f16x2;
typedef __attribute__((ext_vector_type(4))) float f32x4;

#define LDW 136  // f16 LDS row stride for gate kernel

// bf16 helpers (RNE, finite inputs)
__device__ __forceinline__ unsigned int pack_bf16(float lo, float hi) {
    unsigned int a = __float_as_uint(lo), b = __float_as_uint(hi);
    a += 0x7fffu + ((a >> 16) & 1u);
    b += 0x7fffu + ((b >> 16) & 1u);
    return (a >> 16) | (b & 0xffff0000u);
}
__device__ __forceinline__ float bf_lo(unsigned int u) { return __uint_as_float(u << 16); }
__device__ __forceinline__ float bf_hi(unsigned int u) { return __uint_as_float(u & 0xffff0000u); }

// ---------------------------------------------------------------------------
// init: z0[n][d] = bf16 pair of ego[n][2(d&31)], both chains identical at l=0.
// Also: f16 copy of ego for the gate gather (same RNE cast the gate kernel
// used to do inline — bit-identical numerics, half the gather bytes), plus
// winner=-1, deg=0, gate_sum=0 (fused zero-fill kernels).
// ---------------------------------------------------------------------------
__global__ void init_kernel(const float* __restrict__ user, const float* __restrict__ item,
                            unsigned int* __restrict__ z0, _Float16* __restrict__ ego16,
                            int* __restrict__ winner, int* __restrict__ deg,
                            double* __restrict__ gate_sum) {
    int j = blockIdx.x * blockDim.x + threadIdx.x;
    if (j < NN * DD) {
        int n = j >> 6, d = j & 63, dp = d & 31;
        const float* ego = (n < NUM_USERS) ? user + (size_t)n * 64
                                           : item + (size_t)(n - NUM_USERS) * 64;
        float2 e = *(const float2*)(ego + 2 * dp);
        z0[j] = pack_bf16(e.x, e.y);
        if (d < 32) {
            f16x2 h;
            h[0] = (_Float16)e.x;
            h[1] = (_Float16)e.y;
            *(f16x2*)(ego16 + (size_t)n * 64 + 2 * dp) = h;
        }
    }
    if (j < EE) winner[j] = -1;
    if (j < NN) deg[j] = 0;
    if (j == 0) *gate_sum = 0.0;
}

// ---------------------------------------------------------------------------
// gate MLP via f16 MFMA. Gathers pre-converted f16 ego rows (64 B/half-node
// instead of 128 B f32 + inline convert). Single LDS buffer: W1 is staged,
// consumed into bfrag registers, then the buffer is reused for edge tiles
// (halves LDS 35->17.4 KB -> ~2x occupancy for gather latency hiding).
// ---------------------------------------------------------------------------
__global__ __launch_bounds__(256) void gate_kernel(
        const _Float16* __restrict__ ego16,
        const int* __restrict__ rows, const int* __restrict__ cols,
        const int* __restrict__ sidx, const float* __restrict__ eps,
        const float* __restrict__ W1, const float* __restrict__ b1,
        const float* __restrict__ W2, const float* __restrict__ b2,
        float* __restrict__ gate, double* __restrict__ gate_sum) {
    __shared__ _Float16 sh[64 * LDW];
    __shared__ double sdq[4];

    const int t    = threadIdx.x;
    const int lane = t & 63;
    const int w    = t >> 6;
    const int col  = lane & 15;
    const int quad = lane >> 4;

    // stage W1 into sh (transposed: sh[n*LDW + k] = W1[k][n])
    for (int idx = t; idx < 8192; idx += 256) {
        int k = idx >> 6, n = idx & 63;
        sh[n * LDW + k] = (_Float16)W1[idx];
    }
    float b1v[4];
#pragma unroll
    for (int nt = 0; nt < 4; ++nt) b1v[nt] = b1[nt * 16 + col];
    float w2v[4];
#pragma unroll
    for (int nt = 0; nt < 4; ++nt) w2v[nt] = W2[nt * 16 + col];
    const float b2v = b2[0];
    __syncthreads();

    f16x8 bfrag[4][4];
#pragma unroll
    for (int nt = 0; nt < 4; ++nt)
#pragma unroll
        for (int kk = 0; kk < 4; ++kk)
            bfrag[nt][kk] = *(const f16x8*)&sh[(nt * 16 + col) * LDW + kk * 32 + quad * 8];

    double partial = 0.0;
    const int sloc = t >> 2;
    const int part = t & 3;

    for (int tile = blockIdx.x; tile < SS / 64; tile += gridDim.x) {
        const int s0 = tile * 64;
        __syncthreads();  // also protects bfrag reads / prev tile reads
        {
            const int s = s0 + sloc;
            const int e = sidx[s];
            const int node = (part < 2) ? rows[e] : cols[e];
            const f16x8* s8 = (const f16x8*)(ego16 + (size_t)node * 64 + (part & 1) * 32);
            f16x8* dst = (f16x8*)&sh[sloc * LDW + part * 32];
#pragma unroll
            for (int h = 0; h < 4; ++h) dst[h] = s8[h];
        }
        __syncthreads();

        f32x4 acc[4] = {};
        const _Float16* abase = &sh[(w * 16 + col) * LDW + quad * 8];
#pragma unroll
        for (int kk = 0; kk < 4; ++kk) {
            f16x8 a = *(const f16x8*)(abase + kk * 32);
#pragma unroll
            for (int nt = 0; nt < 4; ++nt)
                acc[nt] = __builtin_amdgcn_mfma_f32_16x16x32_f16(a, bfrag[nt][kk], acc[nt], 0, 0, 0);
        }

        float p[4];
#pragma unroll
        for (int r = 0; r < 4; ++r) {
            float sum = 0.f;
#pragma unroll
            for (int nt = 0; nt < 4; ++nt)
                sum = fmaf(fmaxf(acc[nt][r] + b1v[nt], 0.f), w2v[nt], sum);
#pragma unroll
            for (int off = 8; off >= 1; off >>= 1) sum += __shfl_xor(sum, off);
            p[r] = sum + b2v;
        }
        if (col == 0) {
            const int sb = s0 + w * 16 + quad * 4;
            float4 ev4 = *(const float4*)(eps + sb);
            float g4[4];
            const float evs[4] = {ev4.x, ev4.y, ev4.z, ev4.w};
#pragma unroll
            for (int r = 0; r < 4; ++r) {
                float ev  = evs[r] * (1.f - 2e-6f) + 1e-6f;
                float gum = logf(ev) - log1pf(-ev);
                float z   = (p[r] + gum) * (1.f / TAU);
                float g   = 1.f / (1.f + expf(-z)) + EDGE_BIAS;
                g4[r] = g;
                partial += (double)g;
            }
            *(float4*)(gate + sb) = make_float4(g4[0], g4[1], g4[2], g4[3]);
        }
    }

#pragma unroll
    for (int off = 32; off >= 1; off >>= 1) partial += __shfl_xor(partial, off);
    if (lane == 0) sdq[w] = partial;
    __syncthreads();
    if (t == 0) atomicAdd(gate_sum, sdq[0] + sdq[1] + sdq[2] + sdq[3]);
}

// ---------------------------------------------------------------------------
// fused winner (last-write-wins) + degree histogram
// ---------------------------------------------------------------------------
__global__ void whist_kernel(const int* __restrict__ rows, const int* __restrict__ sidx,
                             int* __restrict__ deg, int* __restrict__ winner) {
    int e = blockIdx.x * blockDim.x + threadIdx.x;
    if (e < EE) atomicAdd(&deg[rows[e]], 1);
    if (e < SS) atomicMax(&winner[sidx[e]], e);
}

// ---------------------------------------------------------------------------
// CSR build
// ---------------------------------------------------------------------------
__global__ void scan1_kernel(const int* __restrict__ deg, int* __restrict__ rowptr,
                             int* __restrict__ bsum) {
    __shared__ int sh[256];
    int tid = threadIdx.x;
    int i = blockIdx.x * 256 + tid;
    int v = (i < NN) ? deg[i] : 0;
    sh[tid] = v;
    __syncthreads();
    for (int off = 1; off < 256; off <<= 1) {
        int t = (tid >= off) ? sh[tid - off] : 0;
        __syncthreads();
        sh[tid] += t;
        __syncthreads();
    }
    if (i < NN) rowptr[i] = sh[tid] - v;
    if (tid == 255) bsum[blockIdx.x] = sh[255];
}

__global__ void scan2_kernel(int* __restrict__ bsum) {
    __shared__ int sh[1024];
    int tid = threadIdx.x;
    int v = (tid < NB_SCAN) ? bsum[tid] : 0;
    sh[tid] = v;
    __syncthreads();
    for (int off = 1; off < 1024; off <<= 1) {
        int t = (tid >= off) ? sh[tid - off] : 0;
        __syncthreads();
        sh[tid] += t;
        __syncthreads();
    }
    if (tid < NB_SCAN) bsum[tid] = sh[tid] - v;
}

__global__ void scan3_kernel(int* __restrict__ rowptr, const int* __restrict__ bsum,
                             int* __restrict__ cursor) {
    int i = blockIdx.x * blockDim.x + threadIdx.x;
    if (i < NN) {
        rowptr[i] += bsum[i >> 8];
        cursor[i] = 0;
    }
    if (i == 0) rowptr[NN] = EE;
}

// scatter pre-joins edge payload into CSR order: {col, val, mval, pad}.
// mval computed inline (fused former mvals_kernel).
__global__ void scatter_kernel(const int* __restrict__ rows, const int* __restrict__ cols,
                               const float* __restrict__ vals,
                               const int* __restrict__ winner, const float* __restrict__ gate,
                               const int* __restrict__ rowptr,
                               int* __restrict__ cursor, int4* __restrict__ edata) {
    int e = blockIdx.x * blockDim.x + threadIdx.x;
    if (e < EE) {
        int r = rows[e];
        float v = vals[e];
        int wn = winner[e];
        float mv = (wn >= 0) ? v * gate[wn] : v;
        int pos = rowptr[r] + atomicAdd(&cursor[r], 1);
        edata[pos] = make_int4(cols[e], __float_as_int(v), __float_as_int(mv), 0);
    }
}

// ---------------------------------------------------------------------------
// packed dual-chain gather-SpMM, dwordx4 layout:
// one wave per row; 16 lanes per edge, 4 edges in flight per instruction.
// Each lane loads uint4 (4 dim-pairs = 8 dims of one chain); lanes 0-7 of a
// group carry the unmasked chain, 8-15 the masked chain. Cross-group butterfly
// (shfl_xor 16,32) reduces the 4 edge-slots at row end.
// ---------------------------------------------------------------------------
__global__ __launch_bounds__(256) void spmm_packed_kernel(
        const int* __restrict__ rowptr, const int4* __restrict__ edata,
        const unsigned int* __restrict__ zin, unsigned int* __restrict__ zout) {
    int w = (blockIdx.x * blockDim.x + threadIdx.x) >> 6;
    if (w >= NN) return;
    const int lane = threadIdx.x & 63;
    const int g    = lane >> 4;   // edge slot 0..3
    const int sub  = lane & 15;   // u32 quad within node row
    const int beg = rowptr[w], end = rowptr[w + 1];

    float a[8] = {0.f, 0.f, 0.f, 0.f, 0.f, 0.f, 0.f, 0.f};
    int i = beg;
    for (; i + 8 <= end; i += 8) {
        int4 e0 = edata[i + g];
        int4 e1 = edata[i + 4 + g];
        uint4 p0 = *(const uint4*)(zin + (size_t)e0.x * 64 + sub * 4);
        uint4 p1 = *(const uint4*)(zin + (size_t)e1.x * 64 + sub * 4);
        float w0 = (sub < 8) ? __int_as_float(e0.y) : __int_as_float(e0.z);
        float w1 = (sub < 8) ? __int_as_float(e1.y) : __int_as_float(e1.z);
        a[0] = fmaf(w0, bf_lo(p0.x), a[0]); a[1] = fmaf(w0, bf_hi(p0.x), a[1]);
        a[2] = fmaf(w0, bf_lo(p0.y), a[2]); a[3] = fmaf(w0, bf_hi(p0.y), a[3]);
        a[4] = fmaf(w0, bf_lo(p0.z), a[4]); a[5] = fmaf(w0, bf_hi(p0.z), a[5]);
        a[6] = fmaf(w0, bf_lo(p0.w), a[6]); a[7] = fmaf(w0, bf_hi(p0.w), a[7]);
        a[0] = fmaf(w1, bf_lo(p1.x), a[0]); a[1] = fmaf(w1, bf_hi(p1.x), a[1]);
        a[2] = fmaf(w1, bf_lo(p1.y), a[2]); a[3] = fmaf(w1, bf_hi(p1.y), a[3]);
        a[4] = fmaf(w1, bf_lo(p1.z), a[4]); a[5] = fmaf(w1, bf_hi(p1.z), a[5]);
        a[6] = fmaf(w1, bf_lo(p1.w), a[6]); a[7] = fmaf(w1, bf_hi(p1.w), a[7]);
    }
    for (; i < end; i += 4) {
        int idx = i + g;
        int4 e = edata[(idx < end) ? idx : end - 1];
        float wt = (idx < end) ? ((sub < 8) ? __int_as_float(e.y) : __int_as_float(e.z)) : 0.f;
        uint4 p = *(const uint4*)(zin + (size_t)e.x * 64 + sub * 4);
        a[0] = fmaf(wt, bf_lo(p.x), a[0]); a[1] = fmaf(wt, bf_hi(p.x), a[1]);
        a[2] = fmaf(wt, bf_lo(p.y), a[2]); a[3] = fmaf(wt, bf_hi(p.y), a[3]);
        a[4] = fmaf(wt, bf_lo(p.z), a[4]); a[5] = fmaf(wt, bf_hi(p.z), a[5]);
        a[6] = fmaf(wt, bf_lo(p.w), a[6]); a[7] = fmaf(wt, bf_hi(p.w), a[7]);
    }
#pragma unroll
    for (int j = 0; j < 8; ++j) {
        a[j] += __shfl_xor(a[j], 16);
        a[j] += __shfl_xor(a[j], 32);
    }
    if (lane < 16) {
        uint4 o;
        o.x = pack_bf16(a[0], a[1]);
        o.y = pack_bf16(a[2], a[3]);
        o.z = pack_bf16(a[4], a[5]);
        o.w = pack_bf16(a[6], a[7]);
        *(uint4*)(zout + (size_t)w * 64 + sub * 4) = o;
    }
}

// ---------------------------------------------------------------------------
// fold: out = (ego + l1 + l2 + l3) / 4, split x->outx, y->outy
// ---------------------------------------------------------------------------
__global__ void fold_kernel(const float* __restrict__ user, const float* __restrict__ item,
                            const unsigned int* __restrict__ z1,
                            const unsigned int* __restrict__ z2,
                            const unsigned int* __restrict__ z3,
                            float* __restrict__ outx, float* __restrict__ outy) {
    int j = blockIdx.x * blockDim.x + threadIdx.x;
    if (j >= NN * DD) return;
    int n = j >> 6, d = j & 63, dp = d & 31;
    const float* ego = (n < NUM_USERS) ? user + (size_t)n * 64
                                       : item + (size_t)(n - NUM_USERS) * 64;
    float2 e = *(const float2*)(ego + 2 * dp);
    unsigned int u1 = z1[j], u2 = z2[j], u3 = z3[j];
    float s0 = e.x + bf_lo(u1) + bf_lo(u2) + bf_lo(u3);
    float s1 = e.y + bf_hi(u1) + bf_hi(u2) + bf_hi(u3);
    float* dst = ((d < 32) ? outx : outy) + (size_t)n * 64 + 2 * dp;
    *(float2*)dst = make_float2(s0 * 0.25f, s1 * 0.25f);
}

__global__ void final_kernel(const double* __restrict__ gate_sum, float* __restrict__ out_scalar) {
    if (threadIdx.x == 0) out_scalar[0] = (float)(*gate_sum * (1.0 / (double)SS));
}

extern "C" void kernel_launch(void* const* d_in, const int* in_sizes, int n_in,
                              void* d_out, int out_size, void* d_ws, size_t ws_size,
                              hipStream_t stream) {
    const float* user = (const float*)d_in[0];
    const float* item = (const float*)d_in[1];
    const int*   rows = (const int*)d_in[2];
    const int*   cols = (const int*)d_in[3];
    const float* vals = (const float*)d_in[4];
    const int*   sidx = (const int*)d_in[5];
    const float* eps  = (const float*)d_in[6];
    const float* W1   = (const float*)d_in[7];
    const float* b1   = (const float*)d_in[8];
    const float* W2   = (const float*)d_in[9];
    const float* b2   = (const float*)d_in[10];

    float* out  = (float*)d_out;
    const size_t ND = (size_t)NN * DD;
    float* outx = out;
    float* outy = out + ND;
    float* out_scalar = out + 2 * ND;

    unsigned int* wsu = (unsigned int*)d_ws;
    unsigned int* z0 = wsu;
    unsigned int* z1 = wsu + ND;
    unsigned int* z2 = wsu + 2 * ND;
    int4* edata = (int4*)(wsu + 3 * ND);
    // ego16 (19.2 MB) aliases edata (20 MB): live init->gate; edata written
    // only later by scatter, after gate has completed (same stream).
    _Float16* ego16 = (_Float16*)edata;
    unsigned int* regionA = wsu + 3 * ND + (size_t)EE * 4;
    int*   rowptr = (int*)regionA;                    // 150016 ints (NN+1 used)
    int*   cursor = (int*)regionA + 150016;           // doubles as deg
    float* gate   = (float*)(regionA + 300032);       // SS floats; must outlive scatter
    int*   winner = (int*)(regionA + 700032);         // EE ints
    int*   bsum   = winner + EE;
    double* gate_sum = (double*)(((uintptr_t)(bsum + NB_SCAN) + 7) & ~(uintptr_t)7);

    const int B = 256;
    const int grid_ND = (int)((ND + B - 1) / B);
    const int grid_E  = (EE + B - 1) / B;
    const int grid_N  = (NN + B - 1) / B;
    const int grid_spmm = (int)((NN * 64 + B - 1) / B);

    init_kernel<<<grid_ND, B, 0, stream>>>(user, item, z0, ego16, winner, cursor, gate_sum);
    gate_kernel<<<2048, B, 0, stream>>>(ego16, rows, cols, sidx, eps,
                                        W1, b1, W2, b2, gate, gate_sum);
    whist_kernel<<<grid_E, B, 0, stream>>>(rows, sidx, cursor, winner);
    scan1_kernel<<<NB_SCAN, 256, 0, stream>>>(cursor, rowptr, bsum);
    scan2_kernel<<<1, 1024, 0, stream>>>(bsum);
    scan3_kernel<<<grid_N, B, 0, stream>>>(rowptr, bsum, cursor);
    scatter_kernel<<<grid_E, B, 0, stream>>>(rows, cols, vals, winner, gate, rowptr, cursor, edata);

    spmm_packed_kernel<<<grid_spmm, B, 0, stream>>>(rowptr, edata, z0, z1);
    spmm_packed_kernel<<<grid_spmm, B, 0, stream>>>(rowptr, edata, z1, z2);
    spmm_packed_kernel<<<grid_spmm, B, 0, stream>>>(rowptr, edata, z2, z0);

    fold_kernel<<<grid_ND, B, 0, stream>>>(user, item, z1, z2, z0, outx, outy);
    final_kernel<<<1, 64, 0, stream>>>(gate_sum, out_scalar);
}